// Round 1
// baseline (1645.934 us; speedup 1.0000x reference)
//
#include <hip/hip_runtime.h>
#include <hip/hip_bf16.h>
#include <math.h>

#define D_  1024
#define L_  1024
#define B_  4
#define H_  16
#define HD_ 64

// ---------------------------------------------------------------------------
// Kernel 1: student weight generation
// w[p,o,i] = tanh(wl[p,0]*tw[p,0,o,i] + wl[p,1]*tw[p,1,o,i]) * sc[p,o,i] + sh[p,o,i]
// ---------------------------------------------------------------------------
__global__ __launch_bounds__(256) void wgen_kernel(
    const float* __restrict__ tw, const float* __restrict__ wl,
    const float* __restrict__ sc, const float* __restrict__ sh,
    float* __restrict__ w_out) {
  size_t i4 = (size_t)blockIdx.x * 256 + threadIdx.x;  // float4 index
  size_t e = i4 * 4;                                   // element index
  int p = (int)(e >> 20);                              // D*D = 1<<20
  size_t rem = e & 0xFFFFFu;
  float a0 = wl[p * 2 + 0], a1 = wl[p * 2 + 1];
  float4 t0 = *(const float4*)&tw[((size_t)(p * 2 + 0) << 20) + rem];
  float4 t1 = *(const float4*)&tw[((size_t)(p * 2 + 1) << 20) + rem];
  float4 s4 = *(const float4*)&sc[e];
  float4 h4 = *(const float4*)&sh[e];
  float4 o;
  o.x = tanhf(a0 * t0.x + a1 * t1.x) * s4.x + h4.x;
  o.y = tanhf(a0 * t0.y + a1 * t1.y) * s4.y + h4.y;
  o.z = tanhf(a0 * t0.z + a1 * t1.z) * s4.z + h4.z;
  o.w = tanhf(a0 * t0.w + a1 * t1.w) * s4.w + h4.w;
  *(float4*)&w_out[e] = o;
}

// ---------------------------------------------------------------------------
// Kernel 2: student bias generation (3*1024 elements)
// ---------------------------------------------------------------------------
__global__ __launch_bounds__(256) void bgen_kernel(
    const float* __restrict__ tb, const float* __restrict__ wl,
    const float* __restrict__ sc, const float* __restrict__ sh,
    float* __restrict__ b_out) {
  int i = blockIdx.x * 256 + threadIdx.x;  // 0..3071
  int p = i >> 10;
  int o = i & 1023;
  float v = tanhf(wl[p * 2 + 0] * tb[(p * 2 + 0) * D_ + o] +
                  wl[p * 2 + 1] * tb[(p * 2 + 1) * D_ + o]);
  b_out[i] = v * sc[i] + sh[i];
}

// ---------------------------------------------------------------------------
// Kernel 3: QKV projection GEMM.
// Y[m, n] = sum_k hs[m, k] * w[n, k] + bias[n]
// M = B*L = 4096, N = 3*D = 3072, K = D = 1024.
// Output written directly in [p][b][h][l][hd] layout.
// Tiles 64x64, BK=16, 256 threads, 4x4 micro-tile per thread.
// ---------------------------------------------------------------------------
__global__ __launch_bounds__(256) void proj_kernel(
    const float* __restrict__ hs, const float* __restrict__ w,
    const float* __restrict__ bias, float* __restrict__ qkv) {
  __shared__ float a_lds[16][68];  // [k][m]
  __shared__ float b_lds[16][68];  // [k][n]
  const int tid = threadIdx.x;
  const int n0 = blockIdx.x * 64;
  const int m0 = blockIdx.y * 64;
  const int tm = tid >> 4, tn = tid & 15;
  const int lr = tid >> 2, lc = (tid & 3) * 4;
  float acc[4][4] = {{0.f}};

  for (int k0 = 0; k0 < D_; k0 += 16) {
    const float4 av = *(const float4*)&hs[(size_t)(m0 + lr) * D_ + k0 + lc];
    const float4 bv = *(const float4*)&w[(size_t)(n0 + lr) * D_ + k0 + lc];
    __syncthreads();
    a_lds[lc + 0][lr] = av.x; a_lds[lc + 1][lr] = av.y;
    a_lds[lc + 2][lr] = av.z; a_lds[lc + 3][lr] = av.w;
    b_lds[lc + 0][lr] = bv.x; b_lds[lc + 1][lr] = bv.y;
    b_lds[lc + 2][lr] = bv.z; b_lds[lc + 3][lr] = bv.w;
    __syncthreads();
#pragma unroll
    for (int kk = 0; kk < 16; ++kk) {
      float ar[4];
#pragma unroll
      for (int i = 0; i < 4; ++i) ar[i] = a_lds[kk][tm * 4 + i];
      const float4 b4 = *(const float4*)&b_lds[kk][tn * 4];
      const float br[4] = {b4.x, b4.y, b4.z, b4.w};
#pragma unroll
      for (int i = 0; i < 4; ++i)
#pragma unroll
        for (int j = 0; j < 4; ++j) acc[i][j] += ar[i] * br[j];
    }
  }

  const int p = n0 >> 10;
  const int h = (n0 & 1023) >> 6;
#pragma unroll
  for (int i = 0; i < 4; ++i) {
    const int m = m0 + tm * 4 + i;
    const int bb = m >> 10, l = m & 1023;
    float* dst = qkv + ((size_t)((p * B_ + bb) * H_ + h) * L_ + l) * HD_ + tn * 4;
    float4 ov;
    ov.x = acc[i][0] + bias[n0 + tn * 4 + 0];
    ov.y = acc[i][1] + bias[n0 + tn * 4 + 1];
    ov.z = acc[i][2] + bias[n0 + tn * 4 + 2];
    ov.w = acc[i][3] + bias[n0 + tn * 4 + 3];
    *(float4*)dst = ov;
  }
}

// ---------------------------------------------------------------------------
// Kernel 4: fused attention with relative_key_query position bias.
// One workgroup per (b, h, l-tile of 64). Flash-style over r-tiles of 64.
// score(l,r) = [ q(l)·k(r) + q(l)·e(l-r+1023) + k(r)·e(l-r+1023) ] / 8 + mask(b,r)
//            =  q·(k+e) + k·e   (two fused dots)
// ---------------------------------------------------------------------------
__global__ __launch_bounds__(256) void attn_kernel(
    const float* __restrict__ qkv, const float* __restrict__ mask,
    const float* __restrict__ emb, float* __restrict__ out) {
  __shared__ float q_lds[64][68];
  __shared__ float k_lds[64][68];
  __shared__ float v_lds[64][68];
  __shared__ float e_lds[127][68];
  __shared__ float p_lds[64][65];

  const int tid = threadIdx.x;
  const int b = blockIdx.z, h = blockIdx.y;
  const int l0 = blockIdx.x * 64;

  const float* qb = qkv + (size_t)(b * H_ + h) * (L_ * HD_);
  const float* kb = qkv + (size_t)((B_ + b) * H_ + h) * (L_ * HD_);
  const float* vb = qkv + (size_t)((2 * B_ + b) * H_ + h) * (L_ * HD_);

  const int lr = tid >> 2;        // 0..63
  const int lc = (tid & 3) * 16;  // 0,16,32,48
#pragma unroll
  for (int i = 0; i < 4; ++i) {
    *(float4*)&q_lds[lr][lc + i * 4] =
        *(const float4*)&qb[(size_t)(l0 + lr) * HD_ + lc + i * 4];
  }

  const int row = lr;       // row of the 64-row q tile this thread serves
  const int cg = tid & 3;   // column-group (16 cols each)
  float m_run = -1e30f, l_run = 0.0f;
  float o_acc[16];
#pragma unroll
  for (int j = 0; j < 16; ++j) o_acc[j] = 0.0f;

  for (int rt = 0; rt < 16; ++rt) {
    const int r0 = rt * 64;
    __syncthreads();  // previous PV done with k/v/e/p
#pragma unroll
    for (int i = 0; i < 4; ++i) {
      *(float4*)&k_lds[lr][lc + i * 4] =
          *(const float4*)&kb[(size_t)(r0 + lr) * HD_ + lc + i * 4];
      *(float4*)&v_lds[lr][lc + i * 4] =
          *(const float4*)&vb[(size_t)(r0 + lr) * HD_ + lc + i * 4];
    }
    // emb band: dist = l - r + 1023 spans [dmin, dmin+126] for this tile pair
    const int dmin = l0 - r0 + 960;
    for (int i = tid; i < 127 * 16; i += 256) {
      const int band = i >> 4, c = (i & 15) * 4;
      *(float4*)&e_lds[band][c] =
          *(const float4*)&emb[(size_t)(dmin + band) * HD_ + c];
    }
    __syncthreads();

    // ---- scores: this thread does row `row`, 16 cols cg*16..cg*16+15 ----
    float s[16];
#pragma unroll
    for (int j = 0; j < 16; ++j) s[j] = 0.0f;
    for (int d4 = 0; d4 < 16; ++d4) {
      const float4 q4 = *(const float4*)&q_lds[row][d4 * 4];
#pragma unroll
      for (int j = 0; j < 16; ++j) {
        const int rc = cg * 16 + j;
        const float4 k4 = *(const float4*)&k_lds[rc][d4 * 4];
        const float4 e4 = *(const float4*)&e_lds[row - rc + 63][d4 * 4];
        s[j] += q4.x * (k4.x + e4.x) + k4.x * e4.x;
        s[j] += q4.y * (k4.y + e4.y) + k4.y * e4.y;
        s[j] += q4.z * (k4.z + e4.z) + k4.z * e4.z;
        s[j] += q4.w * (k4.w + e4.w) + k4.w * e4.w;
      }
    }

    // ---- online softmax (4 lanes per row: xor 1,2 reduce) ----
    float mloc = -1e30f;
#pragma unroll
    for (int j = 0; j < 16; ++j) {
      s[j] = s[j] * 0.125f + mask[b * L_ + r0 + cg * 16 + j];
      mloc = fmaxf(mloc, s[j]);
    }
    mloc = fmaxf(mloc, __shfl_xor(mloc, 1));
    mloc = fmaxf(mloc, __shfl_xor(mloc, 2));
    const float m_new = fmaxf(m_run, mloc);
    const float resc = __expf(m_run - m_new);
    float psum = 0.0f;
#pragma unroll
    for (int j = 0; j < 16; ++j) {
      const float pv = __expf(s[j] - m_new);
      p_lds[row][cg * 16 + j] = pv;
      psum += pv;
    }
    psum += __shfl_xor(psum, 1);
    psum += __shfl_xor(psum, 2);
    l_run = l_run * resc + psum;
    m_run = m_new;
#pragma unroll
    for (int j = 0; j < 16; ++j) o_acc[j] *= resc;
    __syncthreads();  // p_lds visible to all

    // ---- PV: this thread owns row `row`, output dims cg*16..cg*16+15 ----
#pragma unroll 4
    for (int r = 0; r < 64; ++r) {
      const float pv = p_lds[row][r];
      const float4 v0 = *(const float4*)&v_lds[r][cg * 16 + 0];
      const float4 v1 = *(const float4*)&v_lds[r][cg * 16 + 4];
      const float4 v2 = *(const float4*)&v_lds[r][cg * 16 + 8];
      const float4 v3 = *(const float4*)&v_lds[r][cg * 16 + 12];
      o_acc[0]  += pv * v0.x; o_acc[1]  += pv * v0.y;
      o_acc[2]  += pv * v0.z; o_acc[3]  += pv * v0.w;
      o_acc[4]  += pv * v1.x; o_acc[5]  += pv * v1.y;
      o_acc[6]  += pv * v1.z; o_acc[7]  += pv * v1.w;
      o_acc[8]  += pv * v2.x; o_acc[9]  += pv * v2.y;
      o_acc[10] += pv * v2.z; o_acc[11] += pv * v2.w;
      o_acc[12] += pv * v3.x; o_acc[13] += pv * v3.y;
      o_acc[14] += pv * v3.z; o_acc[15] += pv * v3.w;
    }
  }

  const float invl = 1.0f / l_run;
  const int l = l0 + row;
  float* ob = out + (size_t)(b * L_ + l) * D_ + h * HD_ + cg * 16;
#pragma unroll
  for (int i = 0; i < 4; ++i) {
    float4 ov;
    ov.x = o_acc[i * 4 + 0] * invl;
    ov.y = o_acc[i * 4 + 1] * invl;
    ov.z = o_acc[i * 4 + 2] * invl;
    ov.w = o_acc[i * 4 + 3] * invl;
    *(float4*)&ob[i * 4] = ov;
  }
}

// ---------------------------------------------------------------------------
extern "C" void kernel_launch(void* const* d_in, const int* in_sizes, int n_in,
                              void* d_out, int out_size, void* d_ws, size_t ws_size,
                              hipStream_t stream) {
  const float* hs   = (const float*)d_in[0];
  const float* mask = (const float*)d_in[1];
  const float* tw   = (const float*)d_in[2];
  const float* wlw  = (const float*)d_in[3];
  const float* scw  = (const float*)d_in[4];
  const float* shw  = (const float*)d_in[5];
  const float* tb   = (const float*)d_in[6];
  const float* wlb  = (const float*)d_in[7];
  const float* scb  = (const float*)d_in[8];
  const float* shb  = (const float*)d_in[9];
  const float* emb  = (const float*)d_in[10];
  float* out = (float*)d_out;

  float* ws  = (float*)d_ws;
  float* w_s = ws;                         // 3*1024*1024 floats
  float* b_s = ws + 3 * 1024 * 1024;       // 3072 floats
  float* qkv = b_s + 3072;                 // 3*4*16*1024*64 floats

  hipLaunchKernelGGL(wgen_kernel, dim3(3072), dim3(256), 0, stream,
                     tw, wlw, scw, shw, w_s);
  hipLaunchKernelGGL(bgen_kernel, dim3(12), dim3(256), 0, stream,
                     tb, wlb, scb, shb, b_s);
  hipLaunchKernelGGL(proj_kernel, dim3(48, 64), dim3(256), 0, stream,
                     hs, w_s, b_s, qkv);
  hipLaunchKernelGGL(attn_kernel, dim3(16, 16, 4), dim3(256), 0, stream,
                     qkv, mask, emb, out);
}

// Round 2
// 536.959 us; speedup vs baseline: 3.0653x; 3.0653x over previous
//
#include <hip/hip_runtime.h>
#include <hip/hip_bf16.h>
#include <math.h>

#define D_  1024
#define L_  1024
#define B_  4
#define H_  16
#define HD_ 64

typedef __attribute__((ext_vector_type(4))) short short4_t;
typedef __attribute__((ext_vector_type(8))) short short8_t;
typedef __attribute__((ext_vector_type(4))) float f4;

__device__ __forceinline__ f4 MF(short8_t a, short8_t b, f4 c) {
  return __builtin_amdgcn_mfma_f32_16x16x32_bf16(a, b, c, 0, 0, 0);
}

__device__ __forceinline__ unsigned fbits(float x) { return __builtin_bit_cast(unsigned, x); }
__device__ __forceinline__ float bf2f(unsigned short u) {
  return __builtin_bit_cast(float, (unsigned)u << 16);
}
__device__ __forceinline__ unsigned pack2hi(float x, float y) {
  return (fbits(x) >> 16) | (fbits(y) & 0xFFFF0000u);
}
__device__ __forceinline__ float bfres(float x) {  // x - trunc_bf16(x)
  return x - __builtin_bit_cast(float, fbits(x) & 0xFFFF0000u);
}

// ---------------------------------------------------------------------------
// Kernel 1: student weight generation (unchanged)
// ---------------------------------------------------------------------------
__global__ __launch_bounds__(256) void wgen_kernel(
    const float* __restrict__ tw, const float* __restrict__ wl,
    const float* __restrict__ sc, const float* __restrict__ sh,
    float* __restrict__ w_out) {
  size_t i4 = (size_t)blockIdx.x * 256 + threadIdx.x;
  size_t e = i4 * 4;
  int p = (int)(e >> 20);
  size_t rem = e & 0xFFFFFu;
  float a0 = wl[p * 2 + 0], a1 = wl[p * 2 + 1];
  float4 t0 = *(const float4*)&tw[((size_t)(p * 2 + 0) << 20) + rem];
  float4 t1 = *(const float4*)&tw[((size_t)(p * 2 + 1) << 20) + rem];
  float4 s4 = *(const float4*)&sc[e];
  float4 h4 = *(const float4*)&sh[e];
  float4 o;
  o.x = tanhf(a0 * t0.x + a1 * t1.x) * s4.x + h4.x;
  o.y = tanhf(a0 * t0.y + a1 * t1.y) * s4.y + h4.y;
  o.z = tanhf(a0 * t0.z + a1 * t1.z) * s4.z + h4.z;
  o.w = tanhf(a0 * t0.w + a1 * t1.w) * s4.w + h4.w;
  *(float4*)&w_out[e] = o;
}

// ---------------------------------------------------------------------------
// Kernel 2: student bias generation (unchanged)
// ---------------------------------------------------------------------------
__global__ __launch_bounds__(256) void bgen_kernel(
    const float* __restrict__ tb, const float* __restrict__ wl,
    const float* __restrict__ sc, const float* __restrict__ sh,
    float* __restrict__ b_out) {
  int i = blockIdx.x * 256 + threadIdx.x;
  int p = i >> 10;
  int o = i & 1023;
  float v = tanhf(wl[p * 2 + 0] * tb[(p * 2 + 0) * D_ + o] +
                  wl[p * 2 + 1] * tb[(p * 2 + 1) * D_ + o]);
  b_out[i] = v * sc[i] + sh[i];
}

// ---------------------------------------------------------------------------
// Kernel 3: QKV projection GEMM (unchanged, f32 VALU)
// ---------------------------------------------------------------------------
__global__ __launch_bounds__(256) void proj_kernel(
    const float* __restrict__ hs, const float* __restrict__ w,
    const float* __restrict__ bias, float* __restrict__ qkv) {
  __shared__ float a_lds[16][68];
  __shared__ float b_lds[16][68];
  const int tid = threadIdx.x;
  const int n0 = blockIdx.x * 64;
  const int m0 = blockIdx.y * 64;
  const int tm = tid >> 4, tn = tid & 15;
  const int lr = tid >> 2, lc = (tid & 3) * 4;
  float acc[4][4] = {{0.f}};

  for (int k0 = 0; k0 < D_; k0 += 16) {
    const float4 av = *(const float4*)&hs[(size_t)(m0 + lr) * D_ + k0 + lc];
    const float4 bv = *(const float4*)&w[(size_t)(n0 + lr) * D_ + k0 + lc];
    __syncthreads();
    a_lds[lc + 0][lr] = av.x; a_lds[lc + 1][lr] = av.y;
    a_lds[lc + 2][lr] = av.z; a_lds[lc + 3][lr] = av.w;
    b_lds[lc + 0][lr] = bv.x; b_lds[lc + 1][lr] = bv.y;
    b_lds[lc + 2][lr] = bv.z; b_lds[lc + 3][lr] = bv.w;
    __syncthreads();
#pragma unroll
    for (int kk = 0; kk < 16; ++kk) {
      float ar[4];
#pragma unroll
      for (int i = 0; i < 4; ++i) ar[i] = a_lds[kk][tm * 4 + i];
      const float4 b4 = *(const float4*)&b_lds[kk][tn * 4];
      const float br[4] = {b4.x, b4.y, b4.z, b4.w};
#pragma unroll
      for (int i = 0; i < 4; ++i)
#pragma unroll
        for (int j = 0; j < 4; ++j) acc[i][j] += ar[i] * br[j];
    }
  }

  const int p = n0 >> 10;
  const int h = (n0 & 1023) >> 6;
#pragma unroll
  for (int i = 0; i < 4; ++i) {
    const int m = m0 + tm * 4 + i;
    const int bb = m >> 10, l = m & 1023;
    float* dst = qkv + ((size_t)((p * B_ + bb) * H_ + h) * L_ + l) * HD_ + tn * 4;
    float4 ov;
    ov.x = acc[i][0] + bias[n0 + tn * 4 + 0];
    ov.y = acc[i][1] + bias[n0 + tn * 4 + 1];
    ov.z = acc[i][2] + bias[n0 + tn * 4 + 2];
    ov.w = acc[i][3] + bias[n0 + tn * 4 + 3];
    *(float4*)dst = ov;
  }
}

// ---------------------------------------------------------------------------
// Kernel 4: MFMA fused attention with relative_key_query position bias.
// Grid (8, 16, 4) = (l-pair, h, b); 512 threads = 8 waves.
// Wave w: tile t=w>>2 (64 q-rows), l-half lh=(w>>1)&1, r-half rh=w&1.
// Per r-tile (16 iters):
//   S^T = K*Q^T (bf16x3), U_t^T = E_t*Q^T, W_t^T = E_t*K^T  (band GEMMs)
//   S[r][l] = (S^T + U[l][l-r+63] + W[r][l-r+63])/8 + mask
//   per-(wave r-half) independent online softmax; O^T += V^T*P^T (bf16x3)
// Epilogue: flash-merge the two r-half chains, store.
// ---------------------------------------------------------------------------
__global__ __launch_bounds__(512, 2) void attn_mfma_kernel(
    const float* __restrict__ qkv, const float* __restrict__ mask,
    const float* __restrict__ emb, float* __restrict__ out) {
  __shared__ unsigned short Qh[2][64][68], Ql[2][64][68];
  __shared__ unsigned short Kh[64][68],   Kl[64][68];
  __shared__ unsigned short Vth[64][68],  Vtl[64][68];
  __shared__ unsigned short Eb[192][68];
  __shared__ unsigned short Ub[2][64][132];   // U_t[l][d], d = l-r+63
  __shared__ unsigned short Wb[2][64][132];   // W_t[r][d]

  const int tid  = threadIdx.x;
  const int lane = tid & 63;
  const int wv   = tid >> 6;
  const int t    = wv >> 2;
  const int lh   = (wv >> 1) & 1;
  const int rh   = wv & 1;
  const int l15  = lane & 15;
  const int g    = lane >> 4;        // 0..3

  const int b  = blockIdx.z, h = blockIdx.y;
  const int l0 = blockIdx.x * 128;

  const float* qb = qkv + (size_t)(b * H_ + h) * (L_ * HD_);
  const float* kb = qkv + (size_t)((B_ + b) * H_ + h) * (L_ * HD_);
  const float* vb = qkv + (size_t)((2 * B_ + b) * H_ + h) * (L_ * HD_);
  const float* maskp = mask + b * L_;

  // ---- prologue: stage Q (2 tiles) as bf16 hi/lo ----
#pragma unroll
  for (int it = 0; it < 4; ++it) {
    int f4id = tid + it * 512;           // 0..2047
    int tt  = f4id >> 10;
    int rem = f4id & 1023;
    int row = rem >> 4;
    int c4  = (rem & 15) << 2;
    float4 v = *(const float4*)&qb[(size_t)(l0 + 64 * tt + row) * HD_ + c4];
    uint2 hi; hi.x = pack2hi(v.x, v.y); hi.y = pack2hi(v.z, v.w);
    *(uint2*)&Qh[tt][row][c4] = hi;
    uint2 lo; lo.x = pack2hi(bfres(v.x), bfres(v.y)); lo.y = pack2hi(bfres(v.z), bfres(v.w));
    *(uint2*)&Ql[tt][row][c4] = lo;
  }
  __syncthreads();

  // ---- persistent Q fragments (B-operand of K*Q^T and E*Q^T) ----
  short8_t qfh[2][2], qfl[2][2];   // [nb][kc]
#pragma unroll
  for (int nb = 0; nb < 2; ++nb)
#pragma unroll
    for (int kc = 0; kc < 2; ++kc) {
      const unsigned short* p = &Qh[t][32 * lh + 16 * nb + l15][32 * kc + 4 * g];
      union { short4_t q[2]; short8_t v; } u;
      u.q[0] = *(const short4_t*)p; u.q[1] = *(const short4_t*)(p + 16);
      qfh[nb][kc] = u.v;
      const unsigned short* p2 = &Ql[t][32 * lh + 16 * nb + l15][32 * kc + 4 * g];
      union { short4_t q[2]; short8_t v; } u2;
      u2.q[0] = *(const short4_t*)p2; u2.q[1] = *(const short4_t*)(p2 + 16);
      qfl[nb][kc] = u2.v;
    }

  f4 o_acc[4][2];                  // [d-block][nb]
#pragma unroll
  for (int i = 0; i < 4; ++i)
#pragma unroll
    for (int j = 0; j < 2; ++j) o_acc[i][j] = f4{0.f, 0.f, 0.f, 0.f};
  float mrun[2] = {-3e38f, -3e38f};
  float lsum[2] = {0.f, 0.f};

#pragma unroll 1
  for (int rt = 0; rt < 16; ++rt) {
    const int r0 = rt * 64;
    const int dmin = l0 - r0 + 960;
    __syncthreads();   // previous iter done reading K/V/E/U/W

    // ---- stage K, V^T (hi/lo) ----
#pragma unroll
    for (int it = 0; it < 2; ++it) {
      int f4id = tid + it * 512;         // 0..1023
      int row = f4id >> 4;
      int c4  = (f4id & 15) << 2;
      float4 v = *(const float4*)&kb[(size_t)(r0 + row) * HD_ + c4];
      uint2 hi; hi.x = pack2hi(v.x, v.y); hi.y = pack2hi(v.z, v.w);
      *(uint2*)&Kh[row][c4] = hi;
      uint2 lo; lo.x = pack2hi(bfres(v.x), bfres(v.y)); lo.y = pack2hi(bfres(v.z), bfres(v.w));
      *(uint2*)&Kl[row][c4] = lo;
      float4 vv = *(const float4*)&vb[(size_t)(r0 + row) * HD_ + c4];
      float va[4] = {vv.x, vv.y, vv.z, vv.w};
#pragma unroll
      for (int i = 0; i < 4; ++i) {
        Vth[c4 + i][row] = (unsigned short)(fbits(va[i]) >> 16);
        Vtl[c4 + i][row] = (unsigned short)(fbits(bfres(va[i])) >> 16);
      }
    }
    // ---- stage E band (192 rows, plain bf16) ----
#pragma unroll
    for (int it = 0; it < 6; ++it) {
      int f4id = tid + it * 512;         // 0..3071
      int row = f4id >> 4;
      int c4  = (f4id & 15) << 2;
      int grow = dmin + row;
      grow = grow < 0 ? 0 : (grow > 2046 ? 2046 : grow);
      float4 v = *(const float4*)&emb[(size_t)grow * HD_ + c4];
      uint2 e2; e2.x = pack2hi(v.x, v.y); e2.y = pack2hi(v.z, v.w);
      *(uint2*)&Eb[row][c4] = e2;
    }
    __syncthreads();   // staging visible

    // ---- QK: S^T = K*Q^T (bf16x3) ----
    f4 sacc[2][2];
#pragma unroll
    for (int i = 0; i < 2; ++i)
#pragma unroll
      for (int j = 0; j < 2; ++j) sacc[i][j] = f4{0.f, 0.f, 0.f, 0.f};
#pragma unroll
    for (int mb = 0; mb < 2; ++mb)
#pragma unroll
      for (int kc = 0; kc < 2; ++kc) {
        const unsigned short* ph = &Kh[32 * rh + 16 * mb + l15][32 * kc + 4 * g];
        union { short4_t q[2]; short8_t v; } ua, ub_;
        ua.q[0] = *(const short4_t*)ph; ua.q[1] = *(const short4_t*)(ph + 16);
        const unsigned short* pl = &Kl[32 * rh + 16 * mb + l15][32 * kc + 4 * g];
        ub_.q[0] = *(const short4_t*)pl; ub_.q[1] = *(const short4_t*)(pl + 16);
#pragma unroll
        for (int nb = 0; nb < 2; ++nb) {
          sacc[mb][nb] = MF(ua.v, qfh[nb][kc], sacc[mb][nb]);
          sacc[mb][nb] = MF(ua.v, qfl[nb][kc], sacc[mb][nb]);
          sacc[mb][nb] = MF(ub_.v, qfh[nb][kc], sacc[mb][nb]);
        }
      }

    // ---- U_t^T = E_t * Q^T  (wave covers d-blocks 4*rh..4*rh+3, its l-half) ----
#pragma unroll
    for (int mbu = 0; mbu < 4; ++mbu) {
      const int dblk = 16 * (4 * rh + mbu);
      f4 au[2] = {f4{0.f,0.f,0.f,0.f}, f4{0.f,0.f,0.f,0.f}};
#pragma unroll
      for (int kc = 0; kc < 2; ++kc) {
        const unsigned short* pe = &Eb[64 * t + dblk + l15][32 * kc + 4 * g];
        union { short4_t q[2]; short8_t v; } ue;
        ue.q[0] = *(const short4_t*)pe; ue.q[1] = *(const short4_t*)(pe + 16);
        au[0] = MF(ue.v, qfh[0][kc], au[0]);
        au[1] = MF(ue.v, qfh[1][kc], au[1]);
      }
#pragma unroll
      for (int nb = 0; nb < 2; ++nb) {
        uint2 w2; w2.x = pack2hi(au[nb][0], au[nb][1]); w2.y = pack2hi(au[nb][2], au[nb][3]);
        *(uint2*)&Ub[t][32 * lh + 16 * nb + l15][dblk + 4 * g] = w2;
      }
    }

    // ---- W_t^T = E_t * K^T  (wave covers d-blocks 4*lh..4*lh+3, its r-half) ----
    short8_t bk[2][2];   // [nbw][kc] K_hi rows for this wave's r-half
#pragma unroll
    for (int nbw = 0; nbw < 2; ++nbw)
#pragma unroll
      for (int kc = 0; kc < 2; ++kc) {
        const unsigned short* p = &Kh[32 * rh + 16 * nbw + l15][32 * kc + 4 * g];
        union { short4_t q[2]; short8_t v; } u;
        u.q[0] = *(const short4_t*)p; u.q[1] = *(const short4_t*)(p + 16);
        bk[nbw][kc] = u.v;
      }
#pragma unroll
    for (int mbw = 0; mbw < 4; ++mbw) {
      const int dblk = 16 * (4 * lh + mbw);
      f4 aw[2] = {f4{0.f,0.f,0.f,0.f}, f4{0.f,0.f,0.f,0.f}};
#pragma unroll
      for (int kc = 0; kc < 2; ++kc) {
        const unsigned short* pe = &Eb[64 * t + dblk + l15][32 * kc + 4 * g];
        union { short4_t q[2]; short8_t v; } ue;
        ue.q[0] = *(const short4_t*)pe; ue.q[1] = *(const short4_t*)(pe + 16);
        aw[0] = MF(ue.v, bk[0][kc], aw[0]);
        aw[1] = MF(ue.v, bk[1][kc], aw[1]);
      }
#pragma unroll
      for (int nbw = 0; nbw < 2; ++nbw) {
        uint2 w2; w2.x = pack2hi(aw[nbw][0], aw[nbw][1]); w2.y = pack2hi(aw[nbw][2], aw[nbw][3]);
        *(uint2*)&Wb[t][32 * rh + 16 * nbw + l15][dblk + 4 * g] = w2;
      }
    }
    __syncthreads();   // U/W visible

    // ---- assembly + online softmax (per wave r-half chain) ----
    float4 mk[2];
#pragma unroll
    for (int mb = 0; mb < 2; ++mb)
      mk[mb] = *(const float4*)&maskp[r0 + 32 * rh + 16 * mb + 4 * g];

    float pbuf[2][2][4];
    float al_[2];
#pragma unroll
    for (int nb = 0; nb < 2; ++nb) {
      const int lA = 32 * lh + 16 * nb + l15;
      float sv[2][4];
      float ml = -3e38f;
#pragma unroll
      for (int mb = 0; mb < 2; ++mb) {
        const float mka[4] = {mk[mb].x, mk[mb].y, mk[mb].z, mk[mb].w};
#pragma unroll
        for (int j = 0; j < 4; ++j) {
          const int r = 32 * rh + 16 * mb + 4 * g + j;
          const int d = lA - r + 63;
          float s = (sacc[mb][nb][j] + bf2f(Ub[t][lA][d]) + bf2f(Wb[t][r][d])) * 0.125f
                    + mka[j];
          sv[mb][j] = s;
          ml = fmaxf(ml, s);
        }
      }
      ml = fmaxf(ml, __shfl_xor(ml, 16));
      ml = fmaxf(ml, __shfl_xor(ml, 32));
      const float mn = fmaxf(mrun[nb], ml);
      const float rs = __expf(mrun[nb] - mn);
      float ps = 0.f;
#pragma unroll
      for (int mb = 0; mb < 2; ++mb)
#pragma unroll
        for (int j = 0; j < 4; ++j) {
          const float pv = __expf(sv[mb][j] - mn);
          pbuf[nb][mb][j] = pv;
          ps += pv;
        }
      ps += __shfl_xor(ps, 16);
      ps += __shfl_xor(ps, 32);
      lsum[nb] = lsum[nb] * rs + ps;
      mrun[nb] = mn;
#pragma unroll
      for (int mbd = 0; mbd < 4; ++mbd) {
        o_acc[mbd][nb][0] *= rs; o_acc[mbd][nb][1] *= rs;
        o_acc[mbd][nb][2] *= rs; o_acc[mbd][nb][3] *= rs;
      }
      (void)al_;
    }

    // ---- P fragments (hi/lo) straight from registers ----
    short8_t pf[2], pl_[2];
#pragma unroll
    for (int nb = 0; nb < 2; ++nb) {
      union { unsigned u[4]; short8_t v; } uh, ul;
      uh.u[0] = pack2hi(pbuf[nb][0][0], pbuf[nb][0][1]);
      uh.u[1] = pack2hi(pbuf[nb][0][2], pbuf[nb][0][3]);
      uh.u[2] = pack2hi(pbuf[nb][1][0], pbuf[nb][1][1]);
      uh.u[3] = pack2hi(pbuf[nb][1][2], pbuf[nb][1][3]);
      pf[nb] = uh.v;
      ul.u[0] = pack2hi(bfres(pbuf[nb][0][0]), bfres(pbuf[nb][0][1]));
      ul.u[1] = pack2hi(bfres(pbuf[nb][0][2]), bfres(pbuf[nb][0][3]));
      ul.u[2] = pack2hi(bfres(pbuf[nb][1][0]), bfres(pbuf[nb][1][1]));
      ul.u[3] = pack2hi(bfres(pbuf[nb][1][2]), bfres(pbuf[nb][1][3]));
      pl_[nb] = ul.v;
    }

    // ---- PV: O^T += V^T * P^T (bf16x3), K-chunk = this wave's 32 r ----
#pragma unroll
    for (int mbd = 0; mbd < 4; ++mbd) {
      const unsigned short* ph = &Vth[16 * mbd + l15][32 * rh + 4 * g];
      union { short4_t q[2]; short8_t v; } uh, ul;
      uh.q[0] = *(const short4_t*)ph; uh.q[1] = *(const short4_t*)(ph + 16);
      const unsigned short* pl2 = &Vtl[16 * mbd + l15][32 * rh + 4 * g];
      ul.q[0] = *(const short4_t*)pl2; ul.q[1] = *(const short4_t*)(pl2 + 16);
#pragma unroll
      for (int nb = 0; nb < 2; ++nb) {
        o_acc[mbd][nb] = MF(uh.v, pf[nb], o_acc[mbd][nb]);
        o_acc[mbd][nb] = MF(uh.v, pl_[nb], o_acc[mbd][nb]);
        o_acc[mbd][nb] = MF(ul.v, pf[nb], o_acc[mbd][nb]);
      }
    }
  }

  // ---- epilogue: merge the two r-half chains, store ----
  __syncthreads();
  float* mbuf = (float*)&Wb[0][0][0];     // [wave][nb][l15][2]
  float* obuf = (float*)&Ub[0][0][0];     // [pair][d][l32]
  if (g == 0) {
#pragma unroll
    for (int nb = 0; nb < 2; ++nb) {
      mbuf[((wv * 2 + nb) * 16 + l15) * 2 + 0] = mrun[nb];
      mbuf[((wv * 2 + nb) * 16 + l15) * 2 + 1] = lsum[nb];
    }
  }
  __syncthreads();
  const int pw = wv ^ 1;
  float alpha[2], ltot[2];
#pragma unroll
  for (int nb = 0; nb < 2; ++nb) {
    float m2 = mbuf[((pw * 2 + nb) * 16 + l15) * 2 + 0];
    float s2 = mbuf[((pw * 2 + nb) * 16 + l15) * 2 + 1];
    float M = fmaxf(mrun[nb], m2);
    alpha[nb] = __expf(mrun[nb] - M);
    ltot[nb] = lsum[nb] * alpha[nb] + s2 * __expf(m2 - M);
  }
  const int pair = wv >> 1;
  if (rh == 1) {
#pragma unroll
    for (int mbd = 0; mbd < 4; ++mbd)
#pragma unroll
      for (int nb = 0; nb < 2; ++nb)
#pragma unroll
        for (int j = 0; j < 4; ++j)
          obuf[(pair * 64 + 16 * mbd + 4 * g + j) * 32 + 16 * nb + l15] =
              o_acc[mbd][nb][j] * alpha[nb];
  }
  __syncthreads();
  if (rh == 0) {
#pragma unroll
    for (int mbd = 0; mbd < 4; ++mbd)
#pragma unroll
      for (int nb = 0; nb < 2; ++nb) {
        const int lgl = l0 + 64 * t + 32 * lh + 16 * nb + l15;
        float inv = 1.f / ltot[nb];
        float4 ov;
        float tmp[4];
#pragma unroll
        for (int j = 0; j < 4; ++j)
          tmp[j] = (o_acc[mbd][nb][j] * alpha[nb] +
                    obuf[(pair * 64 + 16 * mbd + 4 * g + j) * 32 + 16 * nb + l15]) * inv;
        ov.x = tmp[0]; ov.y = tmp[1]; ov.z = tmp[2]; ov.w = tmp[3];
        *(float4*)&out[(size_t)(b * L_ + lgl) * D_ + h * HD_ + 16 * mbd + 4 * g] = ov;
      }
  }
}

// ---------------------------------------------------------------------------
extern "C" void kernel_launch(void* const* d_in, const int* in_sizes, int n_in,
                              void* d_out, int out_size, void* d_ws, size_t ws_size,
                              hipStream_t stream) {
  const float* hs   = (const float*)d_in[0];
  const float* mask = (const float*)d_in[1];
  const float* tw   = (const float*)d_in[2];
  const float* wlw  = (const float*)d_in[3];
  const float* scw  = (const float*)d_in[4];
  const float* shw  = (const float*)d_in[5];
  const float* tb   = (const float*)d_in[6];
  const float* wlb  = (const float*)d_in[7];
  const float* scb  = (const float*)d_in[8];
  const float* shb  = (const float*)d_in[9];
  const float* emb  = (const float*)d_in[10];
  float* out = (float*)d_out;

  float* ws  = (float*)d_ws;
  float* w_s = ws;                         // 3*1024*1024 floats
  float* b_s = ws + 3 * 1024 * 1024;       // 3072 floats
  float* qkv = b_s + 3072;                 // 3*4*16*1024*64 floats

  hipLaunchKernelGGL(wgen_kernel, dim3(3072), dim3(256), 0, stream,
                     tw, wlw, scw, shw, w_s);
  hipLaunchKernelGGL(bgen_kernel, dim3(12), dim3(256), 0, stream,
                     tb, wlb, scb, shb, b_s);
  hipLaunchKernelGGL(proj_kernel, dim3(48, 64), dim3(256), 0, stream,
                     hs, w_s, b_s, qkv);
  hipLaunchKernelGGL(attn_mfma_kernel, dim3(8, 16, 4), dim3(512), 0, stream,
                     qkv, mask, emb, out);
}

// Round 3
// 288.994 us; speedup vs baseline: 5.6954x; 1.8580x over previous
//
#include <hip/hip_runtime.h>
#include <hip/hip_bf16.h>
#include <math.h>

#define D_  1024
#define L_  1024
#define B_  4
#define H_  16
#define HD_ 64

typedef __attribute__((ext_vector_type(4))) short short4_t;
typedef __attribute__((ext_vector_type(8))) short short8_t;
typedef __attribute__((ext_vector_type(4))) float f4;

__device__ __forceinline__ f4 MF(short8_t a, short8_t b, f4 c) {
  return __builtin_amdgcn_mfma_f32_16x16x32_bf16(a, b, c, 0, 0, 0);
}

__device__ __forceinline__ unsigned fbits(float x) { return __builtin_bit_cast(unsigned, x); }
__device__ __forceinline__ float bf2f(unsigned short u) {
  return __builtin_bit_cast(float, (unsigned)u << 16);
}
__device__ __forceinline__ unsigned pack2hi(float x, float y) {
  return (fbits(x) >> 16) | (fbits(y) & 0xFFFF0000u);
}
__device__ __forceinline__ float bfres(float x) {  // x - trunc_bf16(x)
  return x - __builtin_bit_cast(float, fbits(x) & 0xFFFF0000u);
}

__device__ __forceinline__ void gload16(const void* g, void* l) {
  __builtin_amdgcn_global_load_lds(
      (const __attribute__((address_space(1))) unsigned*)g,
      (__attribute__((address_space(3))) unsigned*)l, 16, 0, 0);
}

// ---------------------------------------------------------------------------
// Kernel 1: student weight generation -> bf16 hi/lo planes, K-permuted.
// Within each 32-col K block, 4-group q (=k>>2) goes to pos (q&3)*8+((q>>2)&1)*4
// so a ds_read_b128 at [row][8g] yields MFMA frag k={4g..4g+3, 4g+16..4g+19}.
// ---------------------------------------------------------------------------
__global__ __launch_bounds__(256) void wgen_kernel(
    const float* __restrict__ tw, const float* __restrict__ wl,
    const float* __restrict__ sc, const float* __restrict__ sh,
    unsigned short* __restrict__ whi, unsigned short* __restrict__ wlo) {
  size_t i4 = (size_t)blockIdx.x * 256 + threadIdx.x;
  size_t e = i4 * 4;
  int p = (int)(e >> 20);
  size_t rem = e & 0xFFFFFu;
  float a0 = wl[p * 2 + 0], a1 = wl[p * 2 + 1];
  float4 t0 = *(const float4*)&tw[((size_t)(p * 2 + 0) << 20) + rem];
  float4 t1 = *(const float4*)&tw[((size_t)(p * 2 + 1) << 20) + rem];
  float4 s4 = *(const float4*)&sc[e];
  float4 h4 = *(const float4*)&sh[e];
  float4 o;
  o.x = tanhf(a0 * t0.x + a1 * t1.x) * s4.x + h4.x;
  o.y = tanhf(a0 * t0.y + a1 * t1.y) * s4.y + h4.y;
  o.z = tanhf(a0 * t0.z + a1 * t1.z) * s4.z + h4.z;
  o.w = tanhf(a0 * t0.w + a1 * t1.w) * s4.w + h4.w;
  const int q = (int)((e & 1023) >> 2);
  const size_t off = (e & ~(size_t)1023) +
                     (q >> 3) * 32 + (q & 3) * 8 + ((q >> 2) & 1) * 4;
  uint2 hi; hi.x = pack2hi(o.x, o.y); hi.y = pack2hi(o.z, o.w);
  *(uint2*)&whi[off] = hi;
  uint2 lo; lo.x = pack2hi(bfres(o.x), bfres(o.y)); lo.y = pack2hi(bfres(o.z), bfres(o.w));
  *(uint2*)&wlo[off] = lo;
}

// ---------------------------------------------------------------------------
// Kernel 1b: hidden_states -> bf16 hi/lo planes, same K permutation.
// ---------------------------------------------------------------------------
__global__ __launch_bounds__(256) void hscvt_kernel(
    const float* __restrict__ hs,
    unsigned short* __restrict__ hhi, unsigned short* __restrict__ hlo) {
  size_t i4 = (size_t)blockIdx.x * 256 + threadIdx.x;
  size_t e = i4 * 4;
  float4 v = *(const float4*)&hs[e];
  const int q = (int)((e & 1023) >> 2);
  const size_t off = (e & ~(size_t)1023) +
                     (q >> 3) * 32 + (q & 3) * 8 + ((q >> 2) & 1) * 4;
  uint2 hi; hi.x = pack2hi(v.x, v.y); hi.y = pack2hi(v.z, v.w);
  *(uint2*)&hhi[off] = hi;
  uint2 lo; lo.x = pack2hi(bfres(v.x), bfres(v.y)); lo.y = pack2hi(bfres(v.z), bfres(v.w));
  *(uint2*)&hlo[off] = lo;
}

// ---------------------------------------------------------------------------
// Kernel 2: student bias generation (unchanged)
// ---------------------------------------------------------------------------
__global__ __launch_bounds__(256) void bgen_kernel(
    const float* __restrict__ tb, const float* __restrict__ wl,
    const float* __restrict__ sc, const float* __restrict__ sh,
    float* __restrict__ b_out) {
  int i = blockIdx.x * 256 + threadIdx.x;
  int p = i >> 10;
  int o = i & 1023;
  float v = tanhf(wl[p * 2 + 0] * tb[(p * 2 + 0) * D_ + o] +
                  wl[p * 2 + 1] * tb[(p * 2 + 1) * D_ + o]);
  b_out[i] = v * sc[i] + sh[i];
}

// ---------------------------------------------------------------------------
// Kernel 3: QKV projection, bf16x3 MFMA.
// M=4096 (b,l), N=3072 (p,h,hd), K=1024. 128x128 tile, 4 waves, BK=32.
// Staging via global_load_lds width-16 (linear LDS dest; sources pre-permuted
// so frag reads are single conflict-free ds_read_b128).
// ---------------------------------------------------------------------------
__global__ __launch_bounds__(256) void proj_mfma_kernel(
    const unsigned short* __restrict__ Ahp, const unsigned short* __restrict__ Alp,
    const unsigned short* __restrict__ Bhp, const unsigned short* __restrict__ Blp,
    const float* __restrict__ bias, float* __restrict__ qkv) {
  __shared__ unsigned short Ah[128][32], Al[128][32], Bh[128][32], Bl[128][32];
  const int tid  = threadIdx.x;
  const int lane = tid & 63;
  const int wv   = tid >> 6;
  const int wm   = wv >> 1, wn = wv & 1;
  const int l15  = lane & 15, g = lane >> 4;

  // XCD-aware swizzle (768 % 8 == 0 -> simple form is bijective)
  const int bid = (blockIdx.x & 7) * 96 + (blockIdx.x >> 3);
  const int mt = bid & 31, nt = bid >> 5;      // 32 m-tiles x 24 n-tiles
  const int m0 = mt * 128, n0 = nt * 128;

  const unsigned short* gp0 = Ahp + ((size_t)m0 << 10);
  const unsigned short* gp1 = Alp + ((size_t)m0 << 10);
  const unsigned short* gp2 = Bhp + ((size_t)n0 << 10);
  const unsigned short* gp3 = Blp + ((size_t)n0 << 10);
  unsigned short* lp0 = &Ah[0][0];
  unsigned short* lp1 = &Al[0][0];
  unsigned short* lp2 = &Bh[0][0];
  unsigned short* lp3 = &Bl[0][0];

  f4 acc[4][4];
#pragma unroll
  for (int i = 0; i < 4; ++i)
#pragma unroll
    for (int j = 0; j < 4; ++j) acc[i][j] = f4{0.f, 0.f, 0.f, 0.f};

  const int srow = lane >> 2;          // 0..15 within a 16-row group
  const int schk = (lane & 3) << 3;    // ushort offset 0,8,16,24

#pragma unroll 1
  for (int k0 = 0; k0 < D_; k0 += 32) {
#pragma unroll
    for (int r2 = 0; r2 < 2; ++r2) {
      const int rg = wv * 2 + r2;                       // 16-row group 0..7
      const size_t ro = ((size_t)(rg * 16 + srow) << 10) + k0 + schk;
      const int ld = rg * 512;                          // ushorts
      gload16(gp0 + ro, lp0 + ld);
      gload16(gp1 + ro, lp1 + ld);
      gload16(gp2 + ro, lp2 + ld);
      gload16(gp3 + ro, lp3 + ld);
    }
    __syncthreads();   // drains vmcnt -> staged data visible

    short8_t ah[4], al[4], bh[4], bl[4];
#pragma unroll
    for (int i = 0; i < 4; ++i) {
      ah[i] = *(const short8_t*)&Ah[wm * 64 + i * 16 + l15][g * 8];
      al[i] = *(const short8_t*)&Al[wm * 64 + i * 16 + l15][g * 8];
      bh[i] = *(const short8_t*)&Bh[wn * 64 + i * 16 + l15][g * 8];
      bl[i] = *(const short8_t*)&Bl[wn * 64 + i * 16 + l15][g * 8];
    }
#pragma unroll
    for (int mi = 0; mi < 4; ++mi)
#pragma unroll
      for (int ni = 0; ni < 4; ++ni) {
        acc[mi][ni] = MF(ah[mi], bh[ni], acc[mi][ni]);
        acc[mi][ni] = MF(ah[mi], bl[ni], acc[mi][ni]);
        acc[mi][ni] = MF(al[mi], bh[ni], acc[mi][ni]);
      }
    __syncthreads();   // compute done before next-step staging overwrites
  }

  // epilogue: D row (m) = 4g+r within frag, col (n) = l15 (validated mapping)
  const int nbase = n0 + wn * 64;
  float bnv[4];
#pragma unroll
  for (int ni = 0; ni < 4; ++ni) bnv[ni] = bias[nbase + ni * 16 + l15];
#pragma unroll
  for (int mi = 0; mi < 4; ++mi) {
    const int mA = m0 + wm * 64 + mi * 16 + g * 4;
#pragma unroll
    for (int r = 0; r < 4; ++r) {
      const int m = mA + r;
      const int bb = m >> 10, l = m & 1023;
#pragma unroll
      for (int ni = 0; ni < 4; ++ni) {
        const int n = nbase + ni * 16 + l15;
        const int p = n >> 10, h = (n >> 6) & 15, hd = n & 63;
        qkv[(((size_t)((p * B_ + bb) * H_ + h) << 10) + l) * HD_ + hd] =
            acc[mi][ni][r] + bnv[ni];
      }
    }
  }
}

// ---------------------------------------------------------------------------
// Kernel 4: MFMA fused attention (unchanged from round 2, validated)
// ---------------------------------------------------------------------------
__global__ __launch_bounds__(512, 2) void attn_mfma_kernel(
    const float* __restrict__ qkv, const float* __restrict__ mask,
    const float* __restrict__ emb, float* __restrict__ out) {
  __shared__ unsigned short Qh[2][64][68], Ql[2][64][68];
  __shared__ unsigned short Kh[64][68],   Kl[64][68];
  __shared__ unsigned short Vth[64][68],  Vtl[64][68];
  __shared__ unsigned short Eb[192][68];
  __shared__ unsigned short Ub[2][64][132];   // U_t[l][d], d = l-r+63
  __shared__ unsigned short Wb[2][64][132];   // W_t[r][d]

  const int tid  = threadIdx.x;
  const int lane = tid & 63;
  const int wv   = tid >> 6;
  const int t    = wv >> 2;
  const int lh   = (wv >> 1) & 1;
  const int rh   = wv & 1;
  const int l15  = lane & 15;
  const int g    = lane >> 4;        // 0..3

  const int b  = blockIdx.z, h = blockIdx.y;
  const int l0 = blockIdx.x * 128;

  const float* qb = qkv + (size_t)(b * H_ + h) * (L_ * HD_);
  const float* kb = qkv + (size_t)((B_ + b) * H_ + h) * (L_ * HD_);
  const float* vb = qkv + (size_t)((2 * B_ + b) * H_ + h) * (L_ * HD_);
  const float* maskp = mask + b * L_;

#pragma unroll
  for (int it = 0; it < 4; ++it) {
    int f4id = tid + it * 512;
    int tt  = f4id >> 10;
    int rem = f4id & 1023;
    int row = rem >> 4;
    int c4  = (rem & 15) << 2;
    float4 v = *(const float4*)&qb[(size_t)(l0 + 64 * tt + row) * HD_ + c4];
    uint2 hi; hi.x = pack2hi(v.x, v.y); hi.y = pack2hi(v.z, v.w);
    *(uint2*)&Qh[tt][row][c4] = hi;
    uint2 lo; lo.x = pack2hi(bfres(v.x), bfres(v.y)); lo.y = pack2hi(bfres(v.z), bfres(v.w));
    *(uint2*)&Ql[tt][row][c4] = lo;
  }
  __syncthreads();

  short8_t qfh[2][2], qfl[2][2];
#pragma unroll
  for (int nb = 0; nb < 2; ++nb)
#pragma unroll
    for (int kc = 0; kc < 2; ++kc) {
      const unsigned short* p = &Qh[t][32 * lh + 16 * nb + l15][32 * kc + 4 * g];
      union { short4_t q[2]; short8_t v; } u;
      u.q[0] = *(const short4_t*)p; u.q[1] = *(const short4_t*)(p + 16);
      qfh[nb][kc] = u.v;
      const unsigned short* p2 = &Ql[t][32 * lh + 16 * nb + l15][32 * kc + 4 * g];
      union { short4_t q[2]; short8_t v; } u2;
      u2.q[0] = *(const short4_t*)p2; u2.q[1] = *(const short4_t*)(p2 + 16);
      qfl[nb][kc] = u2.v;
    }

  f4 o_acc[4][2];
#pragma unroll
  for (int i = 0; i < 4; ++i)
#pragma unroll
    for (int j = 0; j < 2; ++j) o_acc[i][j] = f4{0.f, 0.f, 0.f, 0.f};
  float mrun[2] = {-3e38f, -3e38f};
  float lsum[2] = {0.f, 0.f};

#pragma unroll 1
  for (int rt = 0; rt < 16; ++rt) {
    const int r0 = rt * 64;
    const int dmin = l0 - r0 + 960;
    __syncthreads();

#pragma unroll
    for (int it = 0; it < 2; ++it) {
      int f4id = tid + it * 512;
      int row = f4id >> 4;
      int c4  = (f4id & 15) << 2;
      float4 v = *(const float4*)&kb[(size_t)(r0 + row) * HD_ + c4];
      uint2 hi; hi.x = pack2hi(v.x, v.y); hi.y = pack2hi(v.z, v.w);
      *(uint2*)&Kh[row][c4] = hi;
      uint2 lo; lo.x = pack2hi(bfres(v.x), bfres(v.y)); lo.y = pack2hi(bfres(v.z), bfres(v.w));
      *(uint2*)&Kl[row][c4] = lo;
      float4 vv = *(const float4*)&vb[(size_t)(r0 + row) * HD_ + c4];
      float va[4] = {vv.x, vv.y, vv.z, vv.w};
#pragma unroll
      for (int i = 0; i < 4; ++i) {
        Vth[c4 + i][row] = (unsigned short)(fbits(va[i]) >> 16);
        Vtl[c4 + i][row] = (unsigned short)(fbits(bfres(va[i])) >> 16);
      }
    }
#pragma unroll
    for (int it = 0; it < 6; ++it) {
      int f4id = tid + it * 512;
      int row = f4id >> 4;
      int c4  = (f4id & 15) << 2;
      int grow = dmin + row;
      grow = grow < 0 ? 0 : (grow > 2046 ? 2046 : grow);
      float4 v = *(const float4*)&emb[(size_t)grow * HD_ + c4];
      uint2 e2; e2.x = pack2hi(v.x, v.y); e2.y = pack2hi(v.z, v.w);
      *(uint2*)&Eb[row][c4] = e2;
    }
    __syncthreads();

    f4 sacc[2][2];
#pragma unroll
    for (int i = 0; i < 2; ++i)
#pragma unroll
      for (int j = 0; j < 2; ++j) sacc[i][j] = f4{0.f, 0.f, 0.f, 0.f};
#pragma unroll
    for (int mb = 0; mb < 2; ++mb)
#pragma unroll
      for (int kc = 0; kc < 2; ++kc) {
        const unsigned short* ph = &Kh[32 * rh + 16 * mb + l15][32 * kc + 4 * g];
        union { short4_t q[2]; short8_t v; } ua, ub_;
        ua.q[0] = *(const short4_t*)ph; ua.q[1] = *(const short4_t*)(ph + 16);
        const unsigned short* pl = &Kl[32 * rh + 16 * mb + l15][32 * kc + 4 * g];
        ub_.q[0] = *(const short4_t*)pl; ub_.q[1] = *(const short4_t*)(pl + 16);
#pragma unroll
        for (int nb = 0; nb < 2; ++nb) {
          sacc[mb][nb] = MF(ua.v, qfh[nb][kc], sacc[mb][nb]);
          sacc[mb][nb] = MF(ua.v, qfl[nb][kc], sacc[mb][nb]);
          sacc[mb][nb] = MF(ub_.v, qfh[nb][kc], sacc[mb][nb]);
        }
      }

#pragma unroll
    for (int mbu = 0; mbu < 4; ++mbu) {
      const int dblk = 16 * (4 * rh + mbu);
      f4 au[2] = {f4{0.f,0.f,0.f,0.f}, f4{0.f,0.f,0.f,0.f}};
#pragma unroll
      for (int kc = 0; kc < 2; ++kc) {
        const unsigned short* pe = &Eb[64 * t + dblk + l15][32 * kc + 4 * g];
        union { short4_t q[2]; short8_t v; } ue;
        ue.q[0] = *(const short4_t*)pe; ue.q[1] = *(const short4_t*)(pe + 16);
        au[0] = MF(ue.v, qfh[0][kc], au[0]);
        au[1] = MF(ue.v, qfh[1][kc], au[1]);
      }
#pragma unroll
      for (int nb = 0; nb < 2; ++nb) {
        uint2 w2; w2.x = pack2hi(au[nb][0], au[nb][1]); w2.y = pack2hi(au[nb][2], au[nb][3]);
        *(uint2*)&Ub[t][32 * lh + 16 * nb + l15][dblk + 4 * g] = w2;
      }
    }

    short8_t bk[2][2];
#pragma unroll
    for (int nbw = 0; nbw < 2; ++nbw)
#pragma unroll
      for (int kc = 0; kc < 2; ++kc) {
        const unsigned short* p = &Kh[32 * rh + 16 * nbw + l15][32 * kc + 4 * g];
        union { short4_t q[2]; short8_t v; } u;
        u.q[0] = *(const short4_t*)p; u.q[1] = *(const short4_t*)(p + 16);
        bk[nbw][kc] = u.v;
      }
#pragma unroll
    for (int mbw = 0; mbw < 4; ++mbw) {
      const int dblk = 16 * (4 * lh + mbw);
      f4 aw[2] = {f4{0.f,0.f,0.f,0.f}, f4{0.f,0.f,0.f,0.f}};
#pragma unroll
      for (int kc = 0; kc < 2; ++kc) {
        const unsigned short* pe = &Eb[64 * t + dblk + l15][32 * kc + 4 * g];
        union { short4_t q[2]; short8_t v; } ue;
        ue.q[0] = *(const short4_t*)pe; ue.q[1] = *(const short4_t*)(pe + 16);
        aw[0] = MF(ue.v, bk[0][kc], aw[0]);
        aw[1] = MF(ue.v, bk[1][kc], aw[1]);
      }
#pragma unroll
      for (int nbw = 0; nbw < 2; ++nbw) {
        uint2 w2; w2.x = pack2hi(aw[nbw][0], aw[nbw][1]); w2.y = pack2hi(aw[nbw][2], aw[nbw][3]);
        *(uint2*)&Wb[t][32 * rh + 16 * nbw + l15][dblk + 4 * g] = w2;
      }
    }
    __syncthreads();

    float4 mk[2];
#pragma unroll
    for (int mb = 0; mb < 2; ++mb)
      mk[mb] = *(const float4*)&maskp[r0 + 32 * rh + 16 * mb + 4 * g];

    float pbuf[2][2][4];
#pragma unroll
    for (int nb = 0; nb < 2; ++nb) {
      const int lA = 32 * lh + 16 * nb + l15;
      float sv[2][4];
      float ml = -3e38f;
#pragma unroll
      for (int mb = 0; mb < 2; ++mb) {
        const float mka[4] = {mk[mb].x, mk[mb].y, mk[mb].z, mk[mb].w};
#pragma unroll
        for (int j = 0; j < 4; ++j) {
          const int r = 32 * rh + 16 * mb + 4 * g + j;
          const int d = lA - r + 63;
          float s = (sacc[mb][nb][j] + bf2f(Ub[t][lA][d]) + bf2f(Wb[t][r][d])) * 0.125f
                    + mka[j];
          sv[mb][j] = s;
          ml = fmaxf(ml, s);
        }
      }
      ml = fmaxf(ml, __shfl_xor(ml, 16));
      ml = fmaxf(ml, __shfl_xor(ml, 32));
      const float mn = fmaxf(mrun[nb], ml);
      const float rs = __expf(mrun[nb] - mn);
      float ps = 0.f;
#pragma unroll
      for (int mb = 0; mb < 2; ++mb)
#pragma unroll
        for (int j = 0; j < 4; ++j) {
          const float pv = __expf(sv[mb][j] - mn);
          pbuf[nb][mb][j] = pv;
          ps += pv;
        }
      ps += __shfl_xor(ps, 16);
      ps += __shfl_xor(ps, 32);
      lsum[nb] = lsum[nb] * rs + ps;
      mrun[nb] = mn;
#pragma unroll
      for (int mbd = 0; mbd < 4; ++mbd) {
        o_acc[mbd][nb][0] *= rs; o_acc[mbd][nb][1] *= rs;
        o_acc[mbd][nb][2] *= rs; o_acc[mbd][nb][3] *= rs;
      }
    }

    short8_t pf[2], pl_[2];
#pragma unroll
    for (int nb = 0; nb < 2; ++nb) {
      union { unsigned u[4]; short8_t v; } uh, ul;
      uh.u[0] = pack2hi(pbuf[nb][0][0], pbuf[nb][0][1]);
      uh.u[1] = pack2hi(pbuf[nb][0][2], pbuf[nb][0][3]);
      uh.u[2] = pack2hi(pbuf[nb][1][0], pbuf[nb][1][1]);
      uh.u[3] = pack2hi(pbuf[nb][1][2], pbuf[nb][1][3]);
      pf[nb] = uh.v;
      ul.u[0] = pack2hi(bfres(pbuf[nb][0][0]), bfres(pbuf[nb][0][1]));
      ul.u[1] = pack2hi(bfres(pbuf[nb][0][2]), bfres(pbuf[nb][0][3]));
      ul.u[2] = pack2hi(bfres(pbuf[nb][1][0]), bfres(pbuf[nb][1][1]));
      ul.u[3] = pack2hi(bfres(pbuf[nb][1][2]), bfres(pbuf[nb][1][3]));
      pl_[nb] = ul.v;
    }

#pragma unroll
    for (int mbd = 0; mbd < 4; ++mbd) {
      const unsigned short* ph = &Vth[16 * mbd + l15][32 * rh + 4 * g];
      union { short4_t q[2]; short8_t v; } uh, ul;
      uh.q[0] = *(const short4_t*)ph; uh.q[1] = *(const short4_t*)(ph + 16);
      const unsigned short* pl2 = &Vtl[16 * mbd + l15][32 * rh + 4 * g];
      ul.q[0] = *(const short4_t*)pl2; ul.q[1] = *(const short4_t*)(pl2 + 16);
#pragma unroll
      for (int nb = 0; nb < 2; ++nb) {
        o_acc[mbd][nb] = MF(uh.v, pf[nb], o_acc[mbd][nb]);
        o_acc[mbd][nb] = MF(uh.v, pl_[nb], o_acc[mbd][nb]);
        o_acc[mbd][nb] = MF(ul.v, pf[nb], o_acc[mbd][nb]);
      }
    }
  }

  __syncthreads();
  float* mbuf = (float*)&Wb[0][0][0];
  float* obuf = (float*)&Ub[0][0][0];
  if (g == 0) {
#pragma unroll
    for (int nb = 0; nb < 2; ++nb) {
      mbuf[((wv * 2 + nb) * 16 + l15) * 2 + 0] = mrun[nb];
      mbuf[((wv * 2 + nb) * 16 + l15) * 2 + 1] = lsum[nb];
    }
  }
  __syncthreads();
  const int pw = wv ^ 1;
  float alpha[2], ltot[2];
#pragma unroll
  for (int nb = 0; nb < 2; ++nb) {
    float m2 = mbuf[((pw * 2 + nb) * 16 + l15) * 2 + 0];
    float s2 = mbuf[((pw * 2 + nb) * 16 + l15) * 2 + 1];
    float M = fmaxf(mrun[nb], m2);
    alpha[nb] = __expf(mrun[nb] - M);
    ltot[nb] = lsum[nb] * alpha[nb] + s2 * __expf(m2 - M);
  }
  const int pair = wv >> 1;
  if (rh == 1) {
#pragma unroll
    for (int mbd = 0; mbd < 4; ++mbd)
#pragma unroll
      for (int nb = 0; nb < 2; ++nb)
#pragma unroll
        for (int j = 0; j < 4; ++j)
          obuf[(pair * 64 + 16 * mbd + 4 * g + j) * 32 + 16 * nb + l15] =
              o_acc[mbd][nb][j] * alpha[nb];
  }
  __syncthreads();
  if (rh == 0) {
#pragma unroll
    for (int mbd = 0; mbd < 4; ++mbd)
#pragma unroll
      for (int nb = 0; nb < 2; ++nb) {
        const int lgl = l0 + 64 * t + 32 * lh + 16 * nb + l15;
        float inv = 1.f / ltot[nb];
        float4 ov;
        float tmp[4];
#pragma unroll
        for (int j = 0; j < 4; ++j)
          tmp[j] = (o_acc[mbd][nb][j] * alpha[nb] +
                    obuf[(pair * 64 + 16 * mbd + 4 * g + j) * 32 + 16 * nb + l15]) * inv;
        ov.x = tmp[0]; ov.y = tmp[1]; ov.z = tmp[2]; ov.w = tmp[3];
        *(float4*)&out[(size_t)(b * L_ + lgl) * D_ + h * HD_ + 16 * mbd + 4 * g] = ov;
      }
  }
}

// ---------------------------------------------------------------------------
extern "C" void kernel_launch(void* const* d_in, const int* in_sizes, int n_in,
                              void* d_out, int out_size, void* d_ws, size_t ws_size,
                              hipStream_t stream) {
  const float* hs   = (const float*)d_in[0];
  const float* mask = (const float*)d_in[1];
  const float* tw   = (const float*)d_in[2];
  const float* wlw  = (const float*)d_in[3];
  const float* scw  = (const float*)d_in[4];
  const float* shw  = (const float*)d_in[5];
  const float* tb   = (const float*)d_in[6];
  const float* wlb  = (const float*)d_in[7];
  const float* scb  = (const float*)d_in[8];
  const float* shb  = (const float*)d_in[9];
  const float* emb  = (const float*)d_in[10];
  float* out = (float*)d_out;

  float* ws = (float*)d_ws;
  float* qkv = ws;                               // 12582912 f32
  float* b_s = ws + 12582912;                    // 3072 f32
  unsigned short* whi = (unsigned short*)(ws + 12582912 + 3072);
  unsigned short* wlo = whi + 3145728;
  unsigned short* hhi = wlo + 3145728;
  unsigned short* hlo = hhi + 4194304;           // total ~79.7 MB

  hipLaunchKernelGGL(wgen_kernel, dim3(3072), dim3(256), 0, stream,
                     tw, wlw, scw, shw, whi, wlo);
  hipLaunchKernelGGL(hscvt_kernel, dim3(4096), dim3(256), 0, stream,
                     hs, hhi, hlo);
  hipLaunchKernelGGL(bgen_kernel, dim3(12), dim3(256), 0, stream,
                     tb, wlb, scb, shb, b_s);
  hipLaunchKernelGGL(proj_mfma_kernel, dim3(768), dim3(256), 0, stream,
                     hhi, hlo, whi, wlo, b_s, qkv);
  hipLaunchKernelGGL(attn_mfma_kernel, dim3(8, 16, 4), dim3(512), 0, stream,
                     qkv, mask, emb, out);
}